// Round 7
// baseline (423.807 us; speedup 1.0000x reference)
//
#include <hip/hip_runtime.h>

#define F_IN 512
#define HDIM 64
#define NCLS 40
#define NLAYER 4
#define EPS_F 0.2f

typedef __attribute__((ext_vector_type(8))) short short8;
typedef __attribute__((ext_vector_type(4))) float f32x4;
typedef __attribute__((ext_vector_type(8))) unsigned short ushort8;
typedef unsigned long long u64;

__device__ __forceinline__ unsigned short f2bf(float f) {
  unsigned u = __float_as_uint(f);
  u += 0x7FFFu + ((u >> 16) & 1u);  // RNE
  return (unsigned short)(u >> 16);
}
__device__ __forceinline__ float bf2f(unsigned short s) {
  return __uint_as_float(((unsigned)s) << 16);
}

// ---------------- CSR build over 2N virtual rows: key = dst*2 + (src>=nHalf) ----------------
__global__ __launch_bounds__(256) void k_init(int* indeg2, int* fill, int rows2) {
  int i = blockIdx.x * 256 + threadIdx.x;
  if (i < rows2) { indeg2[i] = 0; fill[i] = 0; }
}

__global__ __launch_bounds__(256) void k_hist(const int* __restrict__ src,
                                              const int* __restrict__ dst,
                                              int* indeg2, int nE, int nHalf) {
  int e = blockIdx.x * 256 + threadIdx.x;
  if (e < nE) {
    int key = dst[e] * 2 + (src[e] >= nHalf);
    atomicAdd(&indeg2[key], 1);
  }
}

// per-512-entry sums over indeg2
__global__ __launch_bounds__(256) void k_bsum(const int* __restrict__ indeg2, int* bsum, int rows2) {
  int i0 = blockIdx.x * 512 + threadIdx.x;
  int v = 0;
  if (i0 < rows2) v += indeg2[i0];
  if (i0 + 256 < rows2) v += indeg2[i0 + 256];
#pragma unroll
  for (int off = 32; off > 0; off >>= 1) v += __shfl_xor(v, off, 64);
  __shared__ int s[4];
  if ((threadIdx.x & 63) == 0) s[threadIdx.x >> 6] = v;
  __syncthreads();
  if (threadIdx.x == 0) bsum[blockIdx.x] = s[0] + s[1] + s[2] + s[3];
}

// exclusive scan of <=256 block sums (single block)
__global__ __launch_bounds__(256) void k_bscan(const int* __restrict__ bsum, int* bpre,
                                               int* rowptr2, int nblk, int rows2, int nE) {
  __shared__ int sb[256];
  int t = threadIdx.x;
  int v = (t < nblk) ? bsum[t] : 0;
  sb[t] = v;
  __syncthreads();
  int acc = v;
  for (int off = 1; off < 256; off <<= 1) {
    int o = (t >= off) ? sb[t - off] : 0;
    __syncthreads();
    acc += o;
    sb[t] = acc;
    __syncthreads();
  }
  if (t < nblk) bpre[t] = acc - v;
  if (t == 0) rowptr2[rows2] = nE;
}

// per-chunk scan -> rowptr2 ; plus per-node finish (dinv, P, Q, selfc) using lin1's al/ar
__global__ __launch_bounds__(512) void k_rowptr(const int* __restrict__ indeg2,
                                                const int* __restrict__ bpre,
                                                const float* __restrict__ al,
                                                const float* __restrict__ ar,
                                                int* rowptr2, float* dinv,
                                                float2* P, float2* Q, float* selfc,
                                                int rows2, int nN) {
  __shared__ int sb[512];
  int t = threadIdx.x;
  int i = blockIdx.x * 512 + t;
  int v = (i < rows2) ? indeg2[i] : 0;
  sb[t] = v;
  __syncthreads();
  int acc = v;
  for (int off = 1; off < 512; off <<= 1) {
    int o = (t >= off) ? sb[t - off] : 0;
    __syncthreads();
    acc += o;
    sb[t] = acc;
    __syncthreads();
  }
  if (i < rows2) rowptr2[i] = bpre[blockIdx.x] + acc - v;
  // node-level finish: block b covers nodes [b*256, b*256+256)
  if (t < 256) {
    int n = blockIdx.x * 256 + t;
    if (n < nN) {
      int deg = indeg2[2 * n] + indeg2[2 * n + 1];
      float dv = rsqrtf((float)deg + 1.0f);  // +1 self-loop
      dinv[n] = dv;
      float a = al[n], r = ar[n];
      P[n] = make_float2(a, dv);
      Q[n] = make_float2(r, dv);
      selfc[n] = tanhf(a + r) * dv * dv;
    }
  }
}

__global__ __launch_bounds__(256) void k_scatter(const int* __restrict__ src,
                                                 const int* __restrict__ dst,
                                                 const int* __restrict__ rowptr2, int* fill,
                                                 int* csrsrc, int* csrdst, int nE, int nHalf) {
  int e = blockIdx.x * 256 + threadIdx.x;
  if (e < nE) {
    int s = src[e], d = dst[e];
    int key = d * 2 + (s >= nHalf);
    int p = atomicAdd(&fill[key], 1);
    int q = rowptr2[key] + p;
    csrsrc[q] = s;
    csrdst[q] = d;
  }
}

// ---------------- lin1: hraw = bf16(relu(x @ W1^T + b1)) via bf16 MFMA, fused layer-0 scores ----------------
__global__ __launch_bounds__(256) void k_lin1(const float* __restrict__ x,
                                              const float* __restrict__ W1,
                                              const float* __restrict__ b1,
                                              const float* __restrict__ attl0,
                                              const float* __restrict__ attr0,
                                              unsigned short* __restrict__ hraw,
                                              float* __restrict__ al, float* __restrict__ ar,
                                              int nN) {
  __shared__ unsigned short xs[64 * 64];
  __shared__ unsigned short ws[64 * 64];
  const int t = threadIdx.x;
  const int wv = t >> 6;
  const int l = t & 63;
  const int n0 = blockIdx.x * 64;
  const int srow = t >> 2;
  const int sk4 = (t & 3) * 4;
  const bool xvalid = (n0 + srow) < nN;
  const f32x4* x4 = reinterpret_cast<const f32x4*>(x);
  const f32x4* w4 = reinterpret_cast<const f32x4*>(W1);
  short8* xs8 = reinterpret_cast<short8*>(xs);
  short8* ws8 = reinterpret_cast<short8*>(ws);
  const int wslot0 = srow * 8 + (((t & 3) * 2 + 0) ^ (srow & 7));
  const int wslot1 = srow * 8 + (((t & 3) * 2 + 1) ^ (srow & 7));
  const int arow = l & 15;
  const int kgrp = l >> 4;
  f32x4 acc[4] = {{0.f, 0.f, 0.f, 0.f},
                  {0.f, 0.f, 0.f, 0.f},
                  {0.f, 0.f, 0.f, 0.f},
                  {0.f, 0.f, 0.f, 0.f}};
  f32x4 xa[4], wa[4];
  const f32x4 zero4 = {0.f, 0.f, 0.f, 0.f};
  {
    const size_t xb = (size_t)(n0 + srow) * (F_IN / 4) + sk4;
    const size_t wb = (size_t)srow * (F_IN / 4) + sk4;
#pragma unroll
    for (int r = 0; r < 4; ++r) {
      xa[r] = xvalid ? __builtin_nontemporal_load(&x4[xb + r]) : zero4;
      wa[r] = w4[wb + r];
    }
  }
  for (int c = 0; c < 8; ++c) {
    short8 p0, p1, q0, q1;
#pragma unroll
    for (int r = 0; r < 2; ++r) {
#pragma unroll
      for (int j = 0; j < 4; ++j) {
        p0[r * 4 + j] = (short)f2bf(xa[r][j]);
        p1[r * 4 + j] = (short)f2bf(xa[2 + r][j]);
        q0[r * 4 + j] = (short)f2bf(wa[r][j]);
        q1[r * 4 + j] = (short)f2bf(wa[2 + r][j]);
      }
    }
    xs8[wslot0] = p0;
    xs8[wslot1] = p1;
    ws8[wslot0] = q0;
    ws8[wslot1] = q1;
    __syncthreads();
    if (c < 7) {
      const size_t xb = (size_t)(n0 + srow) * (F_IN / 4) + (c + 1) * 16 + sk4;
      const size_t wb = (size_t)srow * (F_IN / 4) + (c + 1) * 16 + sk4;
#pragma unroll
      for (int r = 0; r < 4; ++r) {
        xa[r] = xvalid ? __builtin_nontemporal_load(&x4[xb + r]) : zero4;
        wa[r] = w4[wb + r];
      }
    }
#pragma unroll
    for (int c2 = 0; c2 < 2; ++c2) {
      const short8 a = xs8[(wv * 16 + arow) * 8 + ((c2 * 4 + kgrp) ^ (arow & 7))];
#pragma unroll
      for (int fs = 0; fs < 4; ++fs) {
        const short8 b = ws8[(fs * 16 + arow) * 8 + ((c2 * 4 + kgrp) ^ (arow & 7))];
        acc[fs] = __builtin_amdgcn_mfma_f32_16x16x32_bf16(a, b, acc[fs], 0, 0, 0);
      }
    }
    __syncthreads();
  }
  // epilogue: relu+bias, bf16 store, fused layer-0 scores
  float psl[4] = {0.f, 0.f, 0.f, 0.f};
  float psr[4] = {0.f, 0.f, 0.f, 0.f};
#pragma unroll
  for (int fs = 0; fs < 4; ++fs) {
    const int feat = fs * 16 + arow;
    const float bias = b1[feat];
    const float atl = attl0[feat];
    const float atr = attr0[feat];
#pragma unroll
    for (int j = 0; j < 4; ++j) {
      const float v = fmaxf(acc[fs][j] + bias, 0.f);
      const int node = n0 + wv * 16 + kgrp * 4 + j;
      if (node < nN) hraw[(size_t)node * HDIM + feat] = f2bf(v);
      psl[j] = fmaf(v, atl, psl[j]);
      psr[j] = fmaf(v, atr, psr[j]);
    }
  }
#pragma unroll
  for (int off = 1; off <= 8; off <<= 1) {
#pragma unroll
    for (int j = 0; j < 4; ++j) {
      psl[j] += __shfl_xor(psl[j], off, 64);
      psr[j] += __shfl_xor(psr[j], off, 64);
    }
  }
  if (arow == 0) {
#pragma unroll
    for (int j = 0; j < 4; ++j) {
      const int node = n0 + wv * 16 + kgrp * 4 + j;
      if (node < nN) {
        al[node] = psl[j];
        ar[node] = psr[j];
      }
    }
  }
}

// ---------------- per-layer edge coefficients: esc[e] = {src, coef} ----------------
__global__ __launch_bounds__(256) void k_coef(const int* __restrict__ csrsrc,
                                              const int* __restrict__ csrdst,
                                              const float2* __restrict__ P,
                                              const float2* __restrict__ Q,
                                              u64* __restrict__ esc, int nE) {
  int e = blockIdx.x * 256 + threadIdx.x;
  if (e < nE) {
    int s = csrsrc[e], d = csrdst[e];
    float2 p = P[s], q = Q[d];
    float c = tanhf(p.x + q.x) * (p.y * q.y);
    u64 v = ((u64)(unsigned)__float_as_int(c) << 32) | (u64)(unsigned)s;
    __builtin_nontemporal_store(v, &esc[e]);
  }
}

// ---------------- two-phase aggregation: wave/dest, 8 edge-groups x 8 lanes ----------------
// PASS 0: edges with src < nHalf (h lower half L2-resident), write f32 partial (nontemporal).
// PASS 1: edges with src >= nHalf, finish: bf16 hout (+ optional next-layer scores).
template <int PASS, bool WNEXT>
__global__ __launch_bounds__(256) void k_agg(const unsigned short* __restrict__ h,
                                             const unsigned short* __restrict__ hraw,
                                             const int* __restrict__ rowptr2,
                                             const u64* __restrict__ esc,
                                             const float* __restrict__ dinv,
                                             float* __restrict__ selfc,
                                             const float* __restrict__ attl_n,
                                             const float* __restrict__ attr_n,
                                             float2* __restrict__ P, float2* __restrict__ Q,
                                             float* __restrict__ hpart,
                                             unsigned short* __restrict__ hout, int nN) {
  const int wid = threadIdx.x >> 6, lane = threadIdx.x & 63;
  const int d = blockIdx.x * 4 + wid;
  if (d >= nN) return;
  const int grp = lane >> 3;
  const int fo = (lane & 7) * 8;
  const size_t base = (size_t)d * HDIM + fo;
  float acc[8] = {};
  if (grp == 0) {
    if (PASS == 0) {
      const float sc = selfc[d];
      const ushort8 hd = *reinterpret_cast<const ushort8*>(&h[base]);
      const ushort8 rw = *reinterpret_cast<const ushort8*>(&hraw[base]);
#pragma unroll
      for (int j = 0; j < 8; ++j) acc[j] = fmaf(bf2f(hd[j]), sc, EPS_F * bf2f(rw[j]));
    } else {
      const f32x4 a0 = __builtin_nontemporal_load(reinterpret_cast<const f32x4*>(&hpart[base]));
      const f32x4 a1 = __builtin_nontemporal_load(reinterpret_cast<const f32x4*>(&hpart[base + 4]));
#pragma unroll
      for (int j = 0; j < 4; ++j) { acc[j] = a0[j]; acc[4 + j] = a1[j]; }
    }
  }
  const int r0 = rowptr2[2 * d + PASS];
  const int r1 = rowptr2[2 * d + PASS + 1];
  int e = r0 + grp;
  for (; e + 8 < r1; e += 16) {
    const u64 v0 = __builtin_nontemporal_load(&esc[e]);
    const u64 v1 = __builtin_nontemporal_load(&esc[e + 8]);
    const int s0 = (int)(unsigned)(v0 & 0xFFFFFFFFull);
    const int s1 = (int)(unsigned)(v1 & 0xFFFFFFFFull);
    const ushort8 h0v = *reinterpret_cast<const ushort8*>(&h[(size_t)s0 * HDIM + fo]);
    const ushort8 h1v = *reinterpret_cast<const ushort8*>(&h[(size_t)s1 * HDIM + fo]);
    const float c0 = __int_as_float((int)(v0 >> 32));
    const float c1 = __int_as_float((int)(v1 >> 32));
#pragma unroll
    for (int j = 0; j < 8; ++j) acc[j] = fmaf(bf2f(h0v[j]), c0, acc[j]);
#pragma unroll
    for (int j = 0; j < 8; ++j) acc[j] = fmaf(bf2f(h1v[j]), c1, acc[j]);
  }
  for (; e < r1; e += 8) {
    const u64 v = __builtin_nontemporal_load(&esc[e]);
    const int s = (int)(unsigned)(v & 0xFFFFFFFFull);
    const ushort8 hv = *reinterpret_cast<const ushort8*>(&h[(size_t)s * HDIM + fo]);
    const float c = __int_as_float((int)(v >> 32));
#pragma unroll
    for (int j = 0; j < 8; ++j) acc[j] = fmaf(bf2f(hv[j]), c, acc[j]);
  }
  // reduce across 8 edge-groups: after this all lanes hold the full slice sum
#pragma unroll
  for (int off = 8; off <= 32; off <<= 1) {
#pragma unroll
    for (int j = 0; j < 8; ++j) acc[j] += __shfl_xor(acc[j], off, 64);
  }
  if (PASS == 0) {
    if (grp == 0) {
      f32x4 a0, a1;
#pragma unroll
      for (int j = 0; j < 4; ++j) { a0[j] = acc[j]; a1[j] = acc[4 + j]; }
      __builtin_nontemporal_store(a0, reinterpret_cast<f32x4*>(&hpart[base]));
      __builtin_nontemporal_store(a1, reinterpret_cast<f32x4*>(&hpart[base + 4]));
    }
    return;
  }
  if (grp == 0) {
    ushort8 o;
#pragma unroll
    for (int j = 0; j < 8; ++j) o[j] = f2bf(acc[j]);
    *reinterpret_cast<ushort8*>(&hout[base]) = o;
  }
  if (WNEXT) {
    float psl = 0.f, psr = 0.f;
#pragma unroll
    for (int j = 0; j < 8; ++j) {
      psl = fmaf(acc[j], attl_n[fo + j], psl);
      psr = fmaf(acc[j], attr_n[fo + j], psr);
    }
#pragma unroll
    for (int off = 1; off <= 4; off <<= 1) {
      psl += __shfl_xor(psl, off, 64);
      psr += __shfl_xor(psr, off, 64);
    }
    if (lane == 0) {
      const float dv = dinv[d];
      P[d] = make_float2(psl, dv);
      Q[d] = make_float2(psr, dv);
      selfc[d] = tanhf(psl + psr) * dv * dv;
    }
  }
}

// ---------------- output: thread-per-node logits + log_softmax ----------------
__global__ __launch_bounds__(256) void k_out(const unsigned short* __restrict__ h,
                                             const float* __restrict__ W2,
                                             const float* __restrict__ b2,
                                             float* __restrict__ out, int nN) {
  __shared__ float w2s[NCLS * HDIM];  // [c][j] row-major
  __shared__ float b2s[NCLS];
  for (int i = threadIdx.x; i < NCLS * HDIM; i += 256) w2s[i] = W2[i];
  if (threadIdx.x < NCLS) b2s[threadIdx.x] = b2[threadIdx.x];
  __syncthreads();
  const int n = blockIdx.x * 256 + threadIdx.x;
  if (n >= nN) return;
  float hr[HDIM];
  const ushort8* hrow = reinterpret_cast<const ushort8*>(&h[(size_t)n * HDIM]);
#pragma unroll
  for (int r = 0; r < 8; ++r) {
    const ushort8 v = hrow[r];
#pragma unroll
    for (int j = 0; j < 8; ++j) hr[r * 8 + j] = bf2f(v[j]);
  }
  const float4* w2s4 = reinterpret_cast<const float4*>(w2s);
  float logits[NCLS];
  float m = -INFINITY;
#pragma unroll
  for (int c = 0; c < NCLS; ++c) {
    float a0 = 0.f, a1 = 0.f, a2 = 0.f, a3 = 0.f;
#pragma unroll
    for (int j4 = 0; j4 < HDIM / 4; j4 += 4) {
      const float4 w0 = w2s4[c * (HDIM / 4) + j4 + 0];
      const float4 w1 = w2s4[c * (HDIM / 4) + j4 + 1];
      const float4 w2v = w2s4[c * (HDIM / 4) + j4 + 2];
      const float4 w3 = w2s4[c * (HDIM / 4) + j4 + 3];
      const int j = j4 * 4;
      a0 = fmaf(hr[j + 0], w0.x, a0);  a0 = fmaf(hr[j + 1], w0.y, a0);
      a0 = fmaf(hr[j + 2], w0.z, a0);  a0 = fmaf(hr[j + 3], w0.w, a0);
      a1 = fmaf(hr[j + 4], w1.x, a1);  a1 = fmaf(hr[j + 5], w1.y, a1);
      a1 = fmaf(hr[j + 6], w1.z, a1);  a1 = fmaf(hr[j + 7], w1.w, a1);
      a2 = fmaf(hr[j + 8], w2v.x, a2); a2 = fmaf(hr[j + 9], w2v.y, a2);
      a2 = fmaf(hr[j + 10], w2v.z, a2); a2 = fmaf(hr[j + 11], w2v.w, a2);
      a3 = fmaf(hr[j + 12], w3.x, a3); a3 = fmaf(hr[j + 13], w3.y, a3);
      a3 = fmaf(hr[j + 14], w3.z, a3); a3 = fmaf(hr[j + 15], w3.w, a3);
    }
    const float lg = (a0 + a1) + (a2 + a3) + b2s[c];
    logits[c] = lg;
    m = fmaxf(m, lg);
  }
  float s = 0.f;
#pragma unroll
  for (int c = 0; c < NCLS; ++c) s += expf(logits[c] - m);
  const float lse = m + logf(s);
  float4* o4 = reinterpret_cast<float4*>(&out[(size_t)n * NCLS]);
#pragma unroll
  for (int c4 = 0; c4 < NCLS / 4; ++c4) {
    float4 o;
    o.x = logits[c4 * 4 + 0] - lse;
    o.y = logits[c4 * 4 + 1] - lse;
    o.z = logits[c4 * 4 + 2] - lse;
    o.w = logits[c4 * 4 + 3] - lse;
    o4[c4] = o;
  }
}

extern "C" void kernel_launch(void* const* d_in, const int* in_sizes, int n_in,
                              void* d_out, int out_size, void* d_ws, size_t ws_size,
                              hipStream_t stream) {
  const float* x = (const float*)d_in[0];
  const int* ei = (const int*)d_in[1];
  const float* W1 = (const float*)d_in[2];
  const float* b1 = (const float*)d_in[3];
  const float* W2 = (const float*)d_in[4];
  const float* b2 = (const float*)d_in[5];
  const float* attl = (const float*)d_in[6];
  const float* attr = (const float*)d_in[7];
  float* out = (float*)d_out;

  const int nN = in_sizes[0] / F_IN;
  const int nE = in_sizes[1] / 2;
  const int nHalf = nN / 2;
  const int rows2 = 2 * nN;
  const int* src = ei;
  const int* dst = ei + nE;

  char* w = (char*)d_ws;
  size_t off = 0;
  auto alloc = [&](size_t bytes) {
    void* p = (void*)(w + off);
    off = (off + bytes + 255) & ~(size_t)255;
    return p;
  };
  unsigned short* hraw = (unsigned short*)alloc((size_t)nN * HDIM * 2);
  unsigned short* hA = (unsigned short*)alloc((size_t)nN * HDIM * 2);
  unsigned short* hB = (unsigned short*)alloc((size_t)nN * HDIM * 2);
  float* hpart = (float*)alloc((size_t)nN * HDIM * 4);
  float2* P = (float2*)alloc((size_t)nN * 8);
  float2* Q = (float2*)alloc((size_t)nN * 8);
  float* selfc = (float*)alloc((size_t)nN * 4);
  float* dinv = (float*)alloc((size_t)nN * 4);
  float* al = (float*)alloc((size_t)nN * 4);
  float* ar = (float*)alloc((size_t)nN * 4);
  int* indeg2 = (int*)alloc((size_t)rows2 * 4);
  int* fill = (int*)alloc((size_t)rows2 * 4);
  int* rowptr2 = (int*)alloc((size_t)(rows2 + 1) * 4);
  int* csrsrc = (int*)alloc((size_t)nE * 4);
  int* csrdst = (int*)alloc((size_t)nE * 4);
  u64* esc = (u64*)alloc((size_t)nE * 8);
  int* bsum = (int*)alloc(2048);
  int* bpre = (int*)alloc(2048);

  const int nb_r2 = (rows2 + 255) / 256;
  const int nb_e = (nE + 255) / 256;
  const int nblk = (rows2 + 511) / 512;  // 196 <= 256
  const int nb4 = (nN + 3) / 4;
  const int nb_n = (nN + 255) / 256;

  // lin1 first (independent of graph), fused layer-0 scores
  k_lin1<<<(nN + 63) / 64, 256, 0, stream>>>(x, W1, b1, attl, attr, hraw, al, ar, nN);
  // CSR build over 2N virtual rows
  k_init<<<nb_r2, 256, 0, stream>>>(indeg2, fill, rows2);
  k_hist<<<nb_e, 256, 0, stream>>>(src, dst, indeg2, nE, nHalf);
  k_bsum<<<nblk, 256, 0, stream>>>(indeg2, bsum, rows2);
  k_bscan<<<1, 256, 0, stream>>>(bsum, bpre, rowptr2, nblk, rows2, nE);
  k_rowptr<<<nblk, 512, 0, stream>>>(indeg2, bpre, al, ar, rowptr2, dinv, P, Q, selfc, rows2, nN);
  k_scatter<<<nb_e, 256, 0, stream>>>(src, dst, rowptr2, fill, csrsrc, csrdst, nE, nHalf);

  const unsigned short* hin = hraw;
  unsigned short* hout = hA;
  for (int l = 0; l < NLAYER; ++l) {
    k_coef<<<nb_e, 256, 0, stream>>>(csrsrc, csrdst, P, Q, esc, nE);
    k_agg<0, false><<<nb4, 256, 0, stream>>>(hin, hraw, rowptr2, esc, dinv, selfc,
                                             nullptr, nullptr, P, Q, hpart, nullptr, nN);
    if (l < NLAYER - 1) {
      k_agg<1, true><<<nb4, 256, 0, stream>>>(hin, hraw, rowptr2, esc, dinv, selfc,
                                              attl + (l + 1) * HDIM, attr + (l + 1) * HDIM,
                                              P, Q, hpart, hout, nN);
    } else {
      k_agg<1, false><<<nb4, 256, 0, stream>>>(hin, hraw, rowptr2, esc, dinv, selfc,
                                               nullptr, nullptr, P, Q, hpart, hout, nN);
    }
    hin = hout;
    hout = (hout == hA) ? hB : hA;
  }
  k_out<<<nb_n, 256, 0, stream>>>(hin, W2, b2, out, nN);
}

// Round 8
// 308.482 us; speedup vs baseline: 1.3738x; 1.3738x over previous
//
#include <hip/hip_runtime.h>

#define F_IN 512
#define HDIM 64
#define NCLS 40
#define NLAYER 4
#define EPS_F 0.2f

typedef __attribute__((ext_vector_type(8))) short short8;
typedef __attribute__((ext_vector_type(4))) float f32x4;
typedef __attribute__((ext_vector_type(8))) unsigned short ushort8;
typedef unsigned long long u64;

__device__ __forceinline__ unsigned short f2bf(float f) {
  unsigned u = __float_as_uint(f);
  u += 0x7FFFu + ((u >> 16) & 1u);  // RNE
  return (unsigned short)(u >> 16);
}
__device__ __forceinline__ float bf2f(unsigned short s) {
  return __uint_as_float(((unsigned)s) << 16);
}

// ---------------- CSR build ----------------
__global__ __launch_bounds__(256) void k_init(int* indeg, int* fill, int nN) {
  int i = blockIdx.x * 256 + threadIdx.x;
  if (i < nN) { indeg[i] = 0; fill[i] = 0; }
}

__global__ __launch_bounds__(256) void k_hist(const int* __restrict__ dst, int* indeg, int nE) {
  int e = blockIdx.x * 256 + threadIdx.x;
  if (e < nE) atomicAdd(&indeg[dst[e]], 1);
}

__global__ __launch_bounds__(256) void k_bsum(const int* __restrict__ indeg, int* bsum, int nN) {
  int i0 = blockIdx.x * 512 + threadIdx.x;
  int v = 0;
  if (i0 < nN) v += indeg[i0];
  if (i0 + 256 < nN) v += indeg[i0 + 256];
#pragma unroll
  for (int off = 32; off > 0; off >>= 1) v += __shfl_xor(v, off, 64);
  __shared__ int s[4];
  if ((threadIdx.x & 63) == 0) s[threadIdx.x >> 6] = v;
  __syncthreads();
  if (threadIdx.x == 0) bsum[blockIdx.x] = s[0] + s[1] + s[2] + s[3];
}

__global__ __launch_bounds__(128) void k_bscan(const int* __restrict__ bsum, int* bpre,
                                               int* rowptr, int nblk, int nN, int nE) {
  __shared__ int sb[128];
  int t = threadIdx.x;
  int v = (t < nblk) ? bsum[t] : 0;
  sb[t] = v;
  __syncthreads();
  int acc = v;
  for (int off = 1; off < 128; off <<= 1) {
    int o = (t >= off) ? sb[t - off] : 0;
    __syncthreads();
    acc += o;
    sb[t] = acc;
    __syncthreads();
  }
  if (t < nblk) bpre[t] = acc - v;
  if (t == 0) rowptr[nN] = nE;
}

// per-chunk scan -> rowptr ; fused per-node finish (dinv, P, Q, selfc) from lin1's al/ar
__global__ __launch_bounds__(512) void k_rowptr(const int* __restrict__ indeg,
                                                const int* __restrict__ bpre,
                                                const float* __restrict__ al,
                                                const float* __restrict__ ar,
                                                int* rowptr, float* dinv,
                                                float2* P, float2* Q, float* selfc, int nN) {
  __shared__ int sb[512];
  int t = threadIdx.x;
  int i = blockIdx.x * 512 + t;
  int v = (i < nN) ? indeg[i] : 0;
  sb[t] = v;
  __syncthreads();
  int acc = v;
  for (int off = 1; off < 512; off <<= 1) {
    int o = (t >= off) ? sb[t - off] : 0;
    __syncthreads();
    acc += o;
    sb[t] = acc;
    __syncthreads();
  }
  if (i < nN) {
    rowptr[i] = bpre[blockIdx.x] + acc - v;
    float dv = rsqrtf((float)v + 1.0f);  // +1 self-loop
    dinv[i] = dv;
    float a = al[i], r = ar[i];
    P[i] = make_float2(a, dv);
    Q[i] = make_float2(r, dv);
    selfc[i] = tanhf(a + r) * dv * dv;
  }
}

__global__ __launch_bounds__(256) void k_scatter(const int* __restrict__ src,
                                                 const int* __restrict__ dst,
                                                 const int* __restrict__ rowptr, int* fill,
                                                 int* csrsrc, int* csrdst, int nE) {
  int e = blockIdx.x * 256 + threadIdx.x;
  if (e < nE) {
    int d = dst[e];
    int p = atomicAdd(&fill[d], 1);
    int q = rowptr[d] + p;
    csrsrc[q] = src[e];
    csrdst[q] = d;
  }
}

// ---------------- lin1: hraw = bf16(relu(x @ W1^T + b1)) via bf16 MFMA, fused layer-0 scores ----------------
__global__ __launch_bounds__(256) void k_lin1(const float* __restrict__ x,
                                              const float* __restrict__ W1,
                                              const float* __restrict__ b1,
                                              const float* __restrict__ attl0,
                                              const float* __restrict__ attr0,
                                              unsigned short* __restrict__ hraw,
                                              float* __restrict__ al, float* __restrict__ ar,
                                              int nN) {
  __shared__ unsigned short xs[64 * 64];
  __shared__ unsigned short ws[64 * 64];
  const int t = threadIdx.x;
  const int wv = t >> 6;
  const int l = t & 63;
  const int n0 = blockIdx.x * 64;
  const int srow = t >> 2;
  const int sk4 = (t & 3) * 4;
  const bool xvalid = (n0 + srow) < nN;
  const f32x4* x4 = reinterpret_cast<const f32x4*>(x);
  const f32x4* w4 = reinterpret_cast<const f32x4*>(W1);
  short8* xs8 = reinterpret_cast<short8*>(xs);
  short8* ws8 = reinterpret_cast<short8*>(ws);
  const int wslot0 = srow * 8 + (((t & 3) * 2 + 0) ^ (srow & 7));
  const int wslot1 = srow * 8 + (((t & 3) * 2 + 1) ^ (srow & 7));
  const int arow = l & 15;
  const int kgrp = l >> 4;
  f32x4 acc[4] = {{0.f, 0.f, 0.f, 0.f},
                  {0.f, 0.f, 0.f, 0.f},
                  {0.f, 0.f, 0.f, 0.f},
                  {0.f, 0.f, 0.f, 0.f}};
  f32x4 xa[4], wa[4];
  const f32x4 zero4 = {0.f, 0.f, 0.f, 0.f};
  {
    const size_t xb = (size_t)(n0 + srow) * (F_IN / 4) + sk4;
    const size_t wb = (size_t)srow * (F_IN / 4) + sk4;
#pragma unroll
    for (int r = 0; r < 4; ++r) {
      xa[r] = xvalid ? x4[xb + r] : zero4;
      wa[r] = w4[wb + r];
    }
  }
  for (int c = 0; c < 8; ++c) {
    short8 p0, p1, q0, q1;
#pragma unroll
    for (int r = 0; r < 2; ++r) {
#pragma unroll
      for (int j = 0; j < 4; ++j) {
        p0[r * 4 + j] = (short)f2bf(xa[r][j]);
        p1[r * 4 + j] = (short)f2bf(xa[2 + r][j]);
        q0[r * 4 + j] = (short)f2bf(wa[r][j]);
        q1[r * 4 + j] = (short)f2bf(wa[2 + r][j]);
      }
    }
    xs8[wslot0] = p0;
    xs8[wslot1] = p1;
    ws8[wslot0] = q0;
    ws8[wslot1] = q1;
    __syncthreads();
    if (c < 7) {
      const size_t xb = (size_t)(n0 + srow) * (F_IN / 4) + (c + 1) * 16 + sk4;
      const size_t wb = (size_t)srow * (F_IN / 4) + (c + 1) * 16 + sk4;
#pragma unroll
      for (int r = 0; r < 4; ++r) {
        xa[r] = xvalid ? x4[xb + r] : zero4;
        wa[r] = w4[wb + r];
      }
    }
#pragma unroll
    for (int c2 = 0; c2 < 2; ++c2) {
      const short8 a = xs8[(wv * 16 + arow) * 8 + ((c2 * 4 + kgrp) ^ (arow & 7))];
#pragma unroll
      for (int fs = 0; fs < 4; ++fs) {
        const short8 b = ws8[(fs * 16 + arow) * 8 + ((c2 * 4 + kgrp) ^ (arow & 7))];
        acc[fs] = __builtin_amdgcn_mfma_f32_16x16x32_bf16(a, b, acc[fs], 0, 0, 0);
      }
    }
    __syncthreads();
  }
  // epilogue: relu+bias, bf16 store, fused layer-0 scores
  float psl[4] = {0.f, 0.f, 0.f, 0.f};
  float psr[4] = {0.f, 0.f, 0.f, 0.f};
#pragma unroll
  for (int fs = 0; fs < 4; ++fs) {
    const int feat = fs * 16 + arow;
    const float bias = b1[feat];
    const float atl = attl0[feat];
    const float atr = attr0[feat];
#pragma unroll
    for (int j = 0; j < 4; ++j) {
      const float v = fmaxf(acc[fs][j] + bias, 0.f);
      const int node = n0 + wv * 16 + kgrp * 4 + j;
      if (node < nN) hraw[(size_t)node * HDIM + feat] = f2bf(v);
      psl[j] = fmaf(v, atl, psl[j]);
      psr[j] = fmaf(v, atr, psr[j]);
    }
  }
#pragma unroll
  for (int off = 1; off <= 8; off <<= 1) {
#pragma unroll
    for (int j = 0; j < 4; ++j) {
      psl[j] += __shfl_xor(psl[j], off, 64);
      psr[j] += __shfl_xor(psr[j], off, 64);
    }
  }
  if (arow == 0) {
#pragma unroll
    for (int j = 0; j < 4; ++j) {
      const int node = n0 + wv * 16 + kgrp * 4 + j;
      if (node < nN) {
        al[node] = psl[j];
        ar[node] = psr[j];
      }
    }
  }
}

// ---------------- per-layer edge coefficients: esc[e] = {coef, src} ----------------
__global__ __launch_bounds__(256) void k_coef(const int* __restrict__ csrsrc,
                                              const int* __restrict__ csrdst,
                                              const float2* __restrict__ P,
                                              const float2* __restrict__ Q,
                                              u64* __restrict__ esc, int nE) {
  int e = blockIdx.x * 256 + threadIdx.x;
  if (e < nE) {
    int s = csrsrc[e], d = csrdst[e];
    float2 p = P[s], q = Q[d];
    float c = tanhf(p.x + q.x) * (p.y * q.y);
    esc[e] = ((u64)(unsigned)__float_as_int(c) << 32) | (u64)(unsigned)s;
  }
}

// ---------------- aggregation: wave/dest, 8 edge-groups x 8 lanes, bf16 gathers ----------------
template <bool WNEXT>
__global__ __launch_bounds__(256) void k_agg(const unsigned short* __restrict__ h,
                                             const unsigned short* __restrict__ hraw,
                                             const int* __restrict__ rowptr,
                                             const u64* __restrict__ esc,
                                             const float* __restrict__ dinv,
                                             float* __restrict__ selfc,
                                             const float* __restrict__ attl_n,
                                             const float* __restrict__ attr_n,
                                             float2* __restrict__ P, float2* __restrict__ Q,
                                             unsigned short* __restrict__ hout, int nN) {
  const int wid = threadIdx.x >> 6, lane = threadIdx.x & 63;
  const int d = blockIdx.x * 4 + wid;
  if (d >= nN) return;
  const int grp = lane >> 3;
  const int fo = (lane & 7) * 8;
  const size_t base = (size_t)d * HDIM + fo;
  float acc[8] = {};
  if (grp == 0) {
    const float sc = selfc[d];
    const ushort8 hd = *reinterpret_cast<const ushort8*>(&h[base]);
    const ushort8 rw = *reinterpret_cast<const ushort8*>(&hraw[base]);
#pragma unroll
    for (int j = 0; j < 8; ++j) acc[j] = fmaf(bf2f(hd[j]), sc, EPS_F * bf2f(rw[j]));
  }
  const int e1 = rowptr[d + 1];
  int e = rowptr[d] + grp;
  for (; e + 8 < e1; e += 16) {
    const u64 v0 = esc[e];
    const u64 v1 = esc[e + 8];
    const int s0 = (int)(unsigned)(v0 & 0xFFFFFFFFull);
    const int s1 = (int)(unsigned)(v1 & 0xFFFFFFFFull);
    const ushort8 h0v = *reinterpret_cast<const ushort8*>(&h[(size_t)s0 * HDIM + fo]);
    const ushort8 h1v = *reinterpret_cast<const ushort8*>(&h[(size_t)s1 * HDIM + fo]);
    const float c0 = __int_as_float((int)(v0 >> 32));
    const float c1 = __int_as_float((int)(v1 >> 32));
#pragma unroll
    for (int j = 0; j < 8; ++j) acc[j] = fmaf(bf2f(h0v[j]), c0, acc[j]);
#pragma unroll
    for (int j = 0; j < 8; ++j) acc[j] = fmaf(bf2f(h1v[j]), c1, acc[j]);
  }
  for (; e < e1; e += 8) {
    const u64 v = esc[e];
    const int s = (int)(unsigned)(v & 0xFFFFFFFFull);
    const ushort8 hv = *reinterpret_cast<const ushort8*>(&h[(size_t)s * HDIM + fo]);
    const float c = __int_as_float((int)(v >> 32));
#pragma unroll
    for (int j = 0; j < 8; ++j) acc[j] = fmaf(bf2f(hv[j]), c, acc[j]);
  }
#pragma unroll
  for (int off = 8; off <= 32; off <<= 1) {
#pragma unroll
    for (int j = 0; j < 8; ++j) acc[j] += __shfl_xor(acc[j], off, 64);
  }
  if (grp == 0) {
    ushort8 o;
#pragma unroll
    for (int j = 0; j < 8; ++j) o[j] = f2bf(acc[j]);
    *reinterpret_cast<ushort8*>(&hout[base]) = o;
  }
  if (WNEXT) {
    float psl = 0.f, psr = 0.f;
#pragma unroll
    for (int j = 0; j < 8; ++j) {
      psl = fmaf(acc[j], attl_n[fo + j], psl);
      psr = fmaf(acc[j], attr_n[fo + j], psr);
    }
#pragma unroll
    for (int off = 1; off <= 4; off <<= 1) {
      psl += __shfl_xor(psl, off, 64);
      psr += __shfl_xor(psr, off, 64);
    }
    if (lane == 0) {
      const float dv = dinv[d];
      P[d] = make_float2(psl, dv);
      Q[d] = make_float2(psr, dv);
      selfc[d] = tanhf(psl + psr) * dv * dv;
    }
  }
}

// ---------------- output: thread-per-node logits + log_softmax ----------------
__global__ __launch_bounds__(256) void k_out(const unsigned short* __restrict__ h,
                                             const float* __restrict__ W2,
                                             const float* __restrict__ b2,
                                             float* __restrict__ out, int nN) {
  __shared__ float w2s[NCLS * HDIM];  // [c][j] row-major
  __shared__ float b2s[NCLS];
  for (int i = threadIdx.x; i < NCLS * HDIM; i += 256) w2s[i] = W2[i];
  if (threadIdx.x < NCLS) b2s[threadIdx.x] = b2[threadIdx.x];
  __syncthreads();
  const int n = blockIdx.x * 256 + threadIdx.x;
  if (n >= nN) return;
  float hr[HDIM];
  const ushort8* hrow = reinterpret_cast<const ushort8*>(&h[(size_t)n * HDIM]);
#pragma unroll
  for (int r = 0; r < 8; ++r) {
    const ushort8 v = hrow[r];
#pragma unroll
    for (int j = 0; j < 8; ++j) hr[r * 8 + j] = bf2f(v[j]);
  }
  const float4* w2s4 = reinterpret_cast<const float4*>(w2s);
  float logits[NCLS];
  float m = -INFINITY;
#pragma unroll
  for (int c = 0; c < NCLS; ++c) {
    float a0 = 0.f, a1 = 0.f, a2 = 0.f, a3 = 0.f;
#pragma unroll
    for (int j4 = 0; j4 < HDIM / 4; j4 += 4) {
      const float4 w0 = w2s4[c * (HDIM / 4) + j4 + 0];
      const float4 w1 = w2s4[c * (HDIM / 4) + j4 + 1];
      const float4 w2v = w2s4[c * (HDIM / 4) + j4 + 2];
      const float4 w3 = w2s4[c * (HDIM / 4) + j4 + 3];
      const int j = j4 * 4;
      a0 = fmaf(hr[j + 0], w0.x, a0);  a0 = fmaf(hr[j + 1], w0.y, a0);
      a0 = fmaf(hr[j + 2], w0.z, a0);  a0 = fmaf(hr[j + 3], w0.w, a0);
      a1 = fmaf(hr[j + 4], w1.x, a1);  a1 = fmaf(hr[j + 5], w1.y, a1);
      a1 = fmaf(hr[j + 6], w1.z, a1);  a1 = fmaf(hr[j + 7], w1.w, a1);
      a2 = fmaf(hr[j + 8], w2v.x, a2); a2 = fmaf(hr[j + 9], w2v.y, a2);
      a2 = fmaf(hr[j + 10], w2v.z, a2); a2 = fmaf(hr[j + 11], w2v.w, a2);
      a3 = fmaf(hr[j + 12], w3.x, a3); a3 = fmaf(hr[j + 13], w3.y, a3);
      a3 = fmaf(hr[j + 14], w3.z, a3); a3 = fmaf(hr[j + 15], w3.w, a3);
    }
    const float lg = (a0 + a1) + (a2 + a3) + b2s[c];
    logits[c] = lg;
    m = fmaxf(m, lg);
  }
  float s = 0.f;
#pragma unroll
  for (int c = 0; c < NCLS; ++c) s += expf(logits[c] - m);
  const float lse = m + logf(s);
  float4* o4 = reinterpret_cast<float4*>(&out[(size_t)n * NCLS]);
#pragma unroll
  for (int c4 = 0; c4 < NCLS / 4; ++c4) {
    float4 o;
    o.x = logits[c4 * 4 + 0] - lse;
    o.y = logits[c4 * 4 + 1] - lse;
    o.z = logits[c4 * 4 + 2] - lse;
    o.w = logits[c4 * 4 + 3] - lse;
    o4[c4] = o;
  }
}

extern "C" void kernel_launch(void* const* d_in, const int* in_sizes, int n_in,
                              void* d_out, int out_size, void* d_ws, size_t ws_size,
                              hipStream_t stream) {
  const float* x = (const float*)d_in[0];
  const int* ei = (const int*)d_in[1];
  const float* W1 = (const float*)d_in[2];
  const float* b1 = (const float*)d_in[3];
  const float* W2 = (const float*)d_in[4];
  const float* b2 = (const float*)d_in[5];
  const float* attl = (const float*)d_in[6];
  const float* attr = (const float*)d_in[7];
  float* out = (float*)d_out;

  const int nN = in_sizes[0] / F_IN;
  const int nE = in_sizes[1] / 2;
  const int* src = ei;
  const int* dst = ei + nE;

  char* w = (char*)d_ws;
  size_t off = 0;
  auto alloc = [&](size_t bytes) {
    void* p = (void*)(w + off);
    off = (off + bytes + 255) & ~(size_t)255;
    return p;
  };
  unsigned short* hraw = (unsigned short*)alloc((size_t)nN * HDIM * 2);
  unsigned short* hA = (unsigned short*)alloc((size_t)nN * HDIM * 2);
  unsigned short* hB = (unsigned short*)alloc((size_t)nN * HDIM * 2);
  float2* P = (float2*)alloc((size_t)nN * 8);
  float2* Q = (float2*)alloc((size_t)nN * 8);
  float* selfc = (float*)alloc((size_t)nN * 4);
  float* dinv = (float*)alloc((size_t)nN * 4);
  float* al = (float*)alloc((size_t)nN * 4);
  float* ar = (float*)alloc((size_t)nN * 4);
  int* indeg = (int*)alloc((size_t)nN * 4);
  int* fill = (int*)alloc((size_t)nN * 4);
  int* rowptr = (int*)alloc((size_t)(nN + 1) * 4);
  int* csrsrc = (int*)alloc((size_t)nE * 4);
  int* csrdst = (int*)alloc((size_t)nE * 4);
  u64* esc = (u64*)alloc((size_t)nE * 8);
  int* bsum = (int*)alloc(1024);
  int* bpre = (int*)alloc(1024);

  const int nb_n = (nN + 255) / 256;
  const int nb_e = (nE + 255) / 256;
  const int nblk = (nN + 511) / 512;  // 98 <= 128
  const int nb4 = (nN + 3) / 4;

  // lin1 first (independent of graph), fused layer-0 scores
  k_lin1<<<(nN + 63) / 64, 256, 0, stream>>>(x, W1, b1, attl, attr, hraw, al, ar, nN);
  // CSR build
  k_init<<<nb_n, 256, 0, stream>>>(indeg, fill, nN);
  k_hist<<<nb_e, 256, 0, stream>>>(dst, indeg, nE);
  k_bsum<<<nblk, 256, 0, stream>>>(indeg, bsum, nN);
  k_bscan<<<1, 128, 0, stream>>>(bsum, bpre, rowptr, nblk, nN, nE);
  k_rowptr<<<nblk, 512, 0, stream>>>(indeg, bpre, al, ar, rowptr, dinv, P, Q, selfc, nN);
  k_scatter<<<nb_e, 256, 0, stream>>>(src, dst, rowptr, fill, csrsrc, csrdst, nE);

  const unsigned short* hin = hraw;
  unsigned short* hout = hA;
  for (int l = 0; l < NLAYER; ++l) {
    k_coef<<<nb_e, 256, 0, stream>>>(csrsrc, csrdst, P, Q, esc, nE);
    if (l < NLAYER - 1) {
      k_agg<true><<<nb4, 256, 0, stream>>>(hin, hraw, rowptr, esc, dinv, selfc,
                                           attl + (l + 1) * HDIM, attr + (l + 1) * HDIM,
                                           P, Q, hout, nN);
    } else {
      k_agg<false><<<nb4, 256, 0, stream>>>(hin, hraw, rowptr, esc, dinv, selfc,
                                            nullptr, nullptr, P, Q, hout, nN);
    }
    hin = hout;
    hout = (hout == hA) ? hB : hA;
  }
  k_out<<<nb_n, 256, 0, stream>>>(hin, W2, b2, out, nN);
}

// Round 9
// 260.336 us; speedup vs baseline: 1.6279x; 1.1849x over previous
//
#include <hip/hip_runtime.h>

#define F_IN 512
#define HDIM 64
#define NCLS 40
#define NLAYER 4
#define EPS_F 0.2f

typedef __attribute__((ext_vector_type(8))) short short8;
typedef __attribute__((ext_vector_type(4))) float f32x4;
typedef __attribute__((ext_vector_type(8))) unsigned short ushort8;
typedef unsigned long long u64;

__device__ __forceinline__ unsigned short f2bf(float f) {
  unsigned u = __float_as_uint(f);
  u += 0x7FFFu + ((u >> 16) & 1u);  // RNE
  return (unsigned short)(u >> 16);
}
__device__ __forceinline__ float bf2f(unsigned short s) {
  return __uint_as_float(((unsigned)s) << 16);
}

// ---------------- CSR build ----------------
__global__ __launch_bounds__(256) void k_init(int* indeg, int nN) {
  int i = blockIdx.x * 256 + threadIdx.x;
  if (i < nN) indeg[i] = 0;
}

// histogram; the atomic's return value is the edge's rank within its dst row
__global__ __launch_bounds__(256) void k_hist(const int* __restrict__ dst, int* indeg,
                                              int* __restrict__ rank, int nE) {
  int e = blockIdx.x * 256 + threadIdx.x;
  if (e < nE) rank[e] = atomicAdd(&indeg[dst[e]], 1);
}

__global__ __launch_bounds__(256) void k_bsum(const int* __restrict__ indeg, int* bsum, int nN) {
  int i0 = blockIdx.x * 512 + threadIdx.x;
  int v = 0;
  if (i0 < nN) v += indeg[i0];
  if (i0 + 256 < nN) v += indeg[i0 + 256];
#pragma unroll
  for (int off = 32; off > 0; off >>= 1) v += __shfl_xor(v, off, 64);
  __shared__ int s[4];
  if ((threadIdx.x & 63) == 0) s[threadIdx.x >> 6] = v;
  __syncthreads();
  if (threadIdx.x == 0) bsum[blockIdx.x] = s[0] + s[1] + s[2] + s[3];
}

__global__ __launch_bounds__(128) void k_bscan(const int* __restrict__ bsum, int* bpre,
                                               int* rowptr, int nblk, int nN, int nE) {
  __shared__ int sb[128];
  int t = threadIdx.x;
  int v = (t < nblk) ? bsum[t] : 0;
  sb[t] = v;
  __syncthreads();
  int acc = v;
  for (int off = 1; off < 128; off <<= 1) {
    int o = (t >= off) ? sb[t - off] : 0;
    __syncthreads();
    acc += o;
    sb[t] = acc;
    __syncthreads();
  }
  if (t < nblk) bpre[t] = acc - v;
  if (t == 0) rowptr[nN] = nE;
}

// per-chunk scan -> rowptr ; fused per-node finish (dinv, P, Q, selfc) from lin1's al/ar
__global__ __launch_bounds__(512) void k_rowptr(const int* __restrict__ indeg,
                                                const int* __restrict__ bpre,
                                                const float* __restrict__ al,
                                                const float* __restrict__ ar,
                                                int* rowptr, float* dinv,
                                                float2* P, float2* Q, float* selfc, int nN) {
  __shared__ int sb[512];
  int t = threadIdx.x;
  int i = blockIdx.x * 512 + t;
  int v = (i < nN) ? indeg[i] : 0;
  sb[t] = v;
  __syncthreads();
  int acc = v;
  for (int off = 1; off < 512; off <<= 1) {
    int o = (t >= off) ? sb[t - off] : 0;
    __syncthreads();
    acc += o;
    sb[t] = acc;
    __syncthreads();
  }
  if (i < nN) {
    rowptr[i] = bpre[blockIdx.x] + acc - v;
    float dv = rsqrtf((float)v + 1.0f);  // +1 self-loop
    dinv[i] = dv;
    float a = al[i], r = ar[i];
    P[i] = make_float2(a, dv);
    Q[i] = make_float2(r, dv);
    selfc[i] = tanhf(a + r) * dv * dv;
  }
}

// atomic-free scatter: q = rowptr[d] + rank[e]; single u64 {dst,src} store
__global__ __launch_bounds__(256) void k_scatter(const int* __restrict__ src,
                                                 const int* __restrict__ dst,
                                                 const int* __restrict__ rank,
                                                 const int* __restrict__ rowptr,
                                                 u64* __restrict__ csr_sd, int nE) {
  int e = blockIdx.x * 256 + threadIdx.x;
  if (e < nE) {
    int s = src[e], d = dst[e];
    int q = rowptr[d] + rank[e];
    csr_sd[q] = ((u64)(unsigned)d << 32) | (u64)(unsigned)s;
  }
}

// ---------------- lin1: hraw = bf16(relu(x @ W1^T + b1)) via bf16 MFMA, fused layer-0 scores ----------------
__global__ __launch_bounds__(256) void k_lin1(const float* __restrict__ x,
                                              const float* __restrict__ W1,
                                              const float* __restrict__ b1,
                                              const float* __restrict__ attl0,
                                              const float* __restrict__ attr0,
                                              unsigned short* __restrict__ hraw,
                                              float* __restrict__ al, float* __restrict__ ar,
                                              int nN) {
  __shared__ unsigned short xs[64 * 64];
  __shared__ unsigned short ws[64 * 64];
  const int t = threadIdx.x;
  const int wv = t >> 6;
  const int l = t & 63;
  const int n0 = blockIdx.x * 64;
  const int srow = t >> 2;
  const int sk4 = (t & 3) * 4;
  const bool xvalid = (n0 + srow) < nN;
  const f32x4* x4 = reinterpret_cast<const f32x4*>(x);
  const f32x4* w4 = reinterpret_cast<const f32x4*>(W1);
  short8* xs8 = reinterpret_cast<short8*>(xs);
  short8* ws8 = reinterpret_cast<short8*>(ws);
  const int wslot0 = srow * 8 + (((t & 3) * 2 + 0) ^ (srow & 7));
  const int wslot1 = srow * 8 + (((t & 3) * 2 + 1) ^ (srow & 7));
  const int arow = l & 15;
  const int kgrp = l >> 4;
  f32x4 acc[4] = {{0.f, 0.f, 0.f, 0.f},
                  {0.f, 0.f, 0.f, 0.f},
                  {0.f, 0.f, 0.f, 0.f},
                  {0.f, 0.f, 0.f, 0.f}};
  f32x4 xa[4], wa[4];
  const f32x4 zero4 = {0.f, 0.f, 0.f, 0.f};
  {
    const size_t xb = (size_t)(n0 + srow) * (F_IN / 4) + sk4;
    const size_t wb = (size_t)srow * (F_IN / 4) + sk4;
#pragma unroll
    for (int r = 0; r < 4; ++r) {
      xa[r] = xvalid ? x4[xb + r] : zero4;
      wa[r] = w4[wb + r];
    }
  }
  for (int c = 0; c < 8; ++c) {
    short8 p0, p1, q0, q1;
#pragma unroll
    for (int r = 0; r < 2; ++r) {
#pragma unroll
      for (int j = 0; j < 4; ++j) {
        p0[r * 4 + j] = (short)f2bf(xa[r][j]);
        p1[r * 4 + j] = (short)f2bf(xa[2 + r][j]);
        q0[r * 4 + j] = (short)f2bf(wa[r][j]);
        q1[r * 4 + j] = (short)f2bf(wa[2 + r][j]);
      }
    }
    xs8[wslot0] = p0;
    xs8[wslot1] = p1;
    ws8[wslot0] = q0;
    ws8[wslot1] = q1;
    __syncthreads();
    if (c < 7) {
      const size_t xb = (size_t)(n0 + srow) * (F_IN / 4) + (c + 1) * 16 + sk4;
      const size_t wb = (size_t)srow * (F_IN / 4) + (c + 1) * 16 + sk4;
#pragma unroll
      for (int r = 0; r < 4; ++r) {
        xa[r] = xvalid ? x4[xb + r] : zero4;
        wa[r] = w4[wb + r];
      }
    }
#pragma unroll
    for (int c2 = 0; c2 < 2; ++c2) {
      const short8 a = xs8[(wv * 16 + arow) * 8 + ((c2 * 4 + kgrp) ^ (arow & 7))];
#pragma unroll
      for (int fs = 0; fs < 4; ++fs) {
        const short8 b = ws8[(fs * 16 + arow) * 8 + ((c2 * 4 + kgrp) ^ (arow & 7))];
        acc[fs] = __builtin_amdgcn_mfma_f32_16x16x32_bf16(a, b, acc[fs], 0, 0, 0);
      }
    }
    __syncthreads();
  }
  // epilogue: relu+bias, bf16 store, fused layer-0 scores
  float psl[4] = {0.f, 0.f, 0.f, 0.f};
  float psr[4] = {0.f, 0.f, 0.f, 0.f};
#pragma unroll
  for (int fs = 0; fs < 4; ++fs) {
    const int feat = fs * 16 + arow;
    const float bias = b1[feat];
    const float atl = attl0[feat];
    const float atr = attr0[feat];
#pragma unroll
    for (int j = 0; j < 4; ++j) {
      const float v = fmaxf(acc[fs][j] + bias, 0.f);
      const int node = n0 + wv * 16 + kgrp * 4 + j;
      if (node < nN) hraw[(size_t)node * HDIM + feat] = f2bf(v);
      psl[j] = fmaf(v, atl, psl[j]);
      psr[j] = fmaf(v, atr, psr[j]);
    }
  }
#pragma unroll
  for (int off = 1; off <= 8; off <<= 1) {
#pragma unroll
    for (int j = 0; j < 4; ++j) {
      psl[j] += __shfl_xor(psl[j], off, 64);
      psr[j] += __shfl_xor(psr[j], off, 64);
    }
  }
  if (arow == 0) {
#pragma unroll
    for (int j = 0; j < 4; ++j) {
      const int node = n0 + wv * 16 + kgrp * 4 + j;
      if (node < nN) {
        al[node] = psl[j];
        ar[node] = psr[j];
      }
    }
  }
}

// ---------------- per-layer edge coefficients: esc[e] = {coef, src} ----------------
__global__ __launch_bounds__(256) void k_coef(const u64* __restrict__ csr_sd,
                                              const float2* __restrict__ P,
                                              const float2* __restrict__ Q,
                                              u64* __restrict__ esc, int nE) {
  int e = blockIdx.x * 256 + threadIdx.x;
  if (e < nE) {
    u64 sd = csr_sd[e];
    int s = (int)(unsigned)(sd & 0xFFFFFFFFull);
    int d = (int)(unsigned)(sd >> 32);
    float2 p = P[s], q = Q[d];
    float c = tanhf(p.x + q.x) * (p.y * q.y);
    esc[e] = ((u64)(unsigned)__float_as_int(c) << 32) | (u64)(unsigned)s;
  }
}

// ---------------- aggregation: wave/dest, 8 edge-groups x 8 lanes, bf16 gathers ----------------
template <bool WNEXT>
__global__ __launch_bounds__(256) void k_agg(const unsigned short* __restrict__ h,
                                             const unsigned short* __restrict__ hraw,
                                             const int* __restrict__ rowptr,
                                             const u64* __restrict__ esc,
                                             const float* __restrict__ dinv,
                                             float* __restrict__ selfc,
                                             const float* __restrict__ attl_n,
                                             const float* __restrict__ attr_n,
                                             float2* __restrict__ P, float2* __restrict__ Q,
                                             unsigned short* __restrict__ hout, int nN) {
  const int wid = threadIdx.x >> 6, lane = threadIdx.x & 63;
  const int d = blockIdx.x * 4 + wid;
  if (d >= nN) return;
  const int grp = lane >> 3;
  const int fo = (lane & 7) * 8;
  const size_t base = (size_t)d * HDIM + fo;
  float acc[8] = {};
  if (grp == 0) {
    const float sc = selfc[d];
    const ushort8 hd = *reinterpret_cast<const ushort8*>(&h[base]);
    const ushort8 rw = *reinterpret_cast<const ushort8*>(&hraw[base]);
#pragma unroll
    for (int j = 0; j < 8; ++j) acc[j] = fmaf(bf2f(hd[j]), sc, EPS_F * bf2f(rw[j]));
  }
  const int e1 = rowptr[d + 1];
  int e = rowptr[d] + grp;
  for (; e + 8 < e1; e += 16) {
    const u64 v0 = esc[e];
    const u64 v1 = esc[e + 8];
    const int s0 = (int)(unsigned)(v0 & 0xFFFFFFFFull);
    const int s1 = (int)(unsigned)(v1 & 0xFFFFFFFFull);
    const ushort8 h0v = *reinterpret_cast<const ushort8*>(&h[(size_t)s0 * HDIM + fo]);
    const ushort8 h1v = *reinterpret_cast<const ushort8*>(&h[(size_t)s1 * HDIM + fo]);
    const float c0 = __int_as_float((int)(v0 >> 32));
    const float c1 = __int_as_float((int)(v1 >> 32));
#pragma unroll
    for (int j = 0; j < 8; ++j) acc[j] = fmaf(bf2f(h0v[j]), c0, acc[j]);
#pragma unroll
    for (int j = 0; j < 8; ++j) acc[j] = fmaf(bf2f(h1v[j]), c1, acc[j]);
  }
  for (; e < e1; e += 8) {
    const u64 v = esc[e];
    const int s = (int)(unsigned)(v & 0xFFFFFFFFull);
    const ushort8 hv = *reinterpret_cast<const ushort8*>(&h[(size_t)s * HDIM + fo]);
    const float c = __int_as_float((int)(v >> 32));
#pragma unroll
    for (int j = 0; j < 8; ++j) acc[j] = fmaf(bf2f(hv[j]), c, acc[j]);
  }
#pragma unroll
  for (int off = 8; off <= 32; off <<= 1) {
#pragma unroll
    for (int j = 0; j < 8; ++j) acc[j] += __shfl_xor(acc[j], off, 64);
  }
  if (grp == 0) {
    ushort8 o;
#pragma unroll
    for (int j = 0; j < 8; ++j) o[j] = f2bf(acc[j]);
    *reinterpret_cast<ushort8*>(&hout[base]) = o;
  }
  if (WNEXT) {
    float psl = 0.f, psr = 0.f;
#pragma unroll
    for (int j = 0; j < 8; ++j) {
      psl = fmaf(acc[j], attl_n[fo + j], psl);
      psr = fmaf(acc[j], attr_n[fo + j], psr);
    }
#pragma unroll
    for (int off = 1; off <= 4; off <<= 1) {
      psl += __shfl_xor(psl, off, 64);
      psr += __shfl_xor(psr, off, 64);
    }
    if (lane == 0) {
      const float dv = dinv[d];
      P[d] = make_float2(psl, dv);
      Q[d] = make_float2(psr, dv);
      selfc[d] = tanhf(psl + psr) * dv * dv;
    }
  }
}

// ---------------- output: thread-per-node logits + log_softmax ----------------
__global__ __launch_bounds__(256) void k_out(const unsigned short* __restrict__ h,
                                             const float* __restrict__ W2,
                                             const float* __restrict__ b2,
                                             float* __restrict__ out, int nN) {
  __shared__ float w2s[NCLS * HDIM];  // [c][j] row-major
  __shared__ float b2s[NCLS];
  for (int i = threadIdx.x; i < NCLS * HDIM; i += 256) w2s[i] = W2[i];
  if (threadIdx.x < NCLS) b2s[threadIdx.x] = b2[threadIdx.x];
  __syncthreads();
  const int n = blockIdx.x * 256 + threadIdx.x;
  if (n >= nN) return;
  float hr[HDIM];
  const ushort8* hrow = reinterpret_cast<const ushort8*>(&h[(size_t)n * HDIM]);
#pragma unroll
  for (int r = 0; r < 8; ++r) {
    const ushort8 v = hrow[r];
#pragma unroll
    for (int j = 0; j < 8; ++j) hr[r * 8 + j] = bf2f(v[j]);
  }
  const float4* w2s4 = reinterpret_cast<const float4*>(w2s);
  float logits[NCLS];
  float m = -INFINITY;
#pragma unroll
  for (int c = 0; c < NCLS; ++c) {
    float a0 = 0.f, a1 = 0.f, a2 = 0.f, a3 = 0.f;
#pragma unroll
    for (int j4 = 0; j4 < HDIM / 4; j4 += 4) {
      const float4 w0 = w2s4[c * (HDIM / 4) + j4 + 0];
      const float4 w1 = w2s4[c * (HDIM / 4) + j4 + 1];
      const float4 w2v = w2s4[c * (HDIM / 4) + j4 + 2];
      const float4 w3 = w2s4[c * (HDIM / 4) + j4 + 3];
      const int j = j4 * 4;
      a0 = fmaf(hr[j + 0], w0.x, a0);  a0 = fmaf(hr[j + 1], w0.y, a0);
      a0 = fmaf(hr[j + 2], w0.z, a0);  a0 = fmaf(hr[j + 3], w0.w, a0);
      a1 = fmaf(hr[j + 4], w1.x, a1);  a1 = fmaf(hr[j + 5], w1.y, a1);
      a1 = fmaf(hr[j + 6], w1.z, a1);  a1 = fmaf(hr[j + 7], w1.w, a1);
      a2 = fmaf(hr[j + 8], w2v.x, a2); a2 = fmaf(hr[j + 9], w2v.y, a2);
      a2 = fmaf(hr[j + 10], w2v.z, a2); a2 = fmaf(hr[j + 11], w2v.w, a2);
      a3 = fmaf(hr[j + 12], w3.x, a3); a3 = fmaf(hr[j + 13], w3.y, a3);
      a3 = fmaf(hr[j + 14], w3.z, a3); a3 = fmaf(hr[j + 15], w3.w, a3);
    }
    const float lg = (a0 + a1) + (a2 + a3) + b2s[c];
    logits[c] = lg;
    m = fmaxf(m, lg);
  }
  float s = 0.f;
#pragma unroll
  for (int c = 0; c < NCLS; ++c) s += expf(logits[c] - m);
  const float lse = m + logf(s);
  float4* o4 = reinterpret_cast<float4*>(&out[(size_t)n * NCLS]);
#pragma unroll
  for (int c4 = 0; c4 < NCLS / 4; ++c4) {
    float4 o;
    o.x = logits[c4 * 4 + 0] - lse;
    o.y = logits[c4 * 4 + 1] - lse;
    o.z = logits[c4 * 4 + 2] - lse;
    o.w = logits[c4 * 4 + 3] - lse;
    o4[c4] = o;
  }
}

extern "C" void kernel_launch(void* const* d_in, const int* in_sizes, int n_in,
                              void* d_out, int out_size, void* d_ws, size_t ws_size,
                              hipStream_t stream) {
  const float* x = (const float*)d_in[0];
  const int* ei = (const int*)d_in[1];
  const float* W1 = (const float*)d_in[2];
  const float* b1 = (const float*)d_in[3];
  const float* W2 = (const float*)d_in[4];
  const float* b2 = (const float*)d_in[5];
  const float* attl = (const float*)d_in[6];
  const float* attr = (const float*)d_in[7];
  float* out = (float*)d_out;

  const int nN = in_sizes[0] / F_IN;
  const int nE = in_sizes[1] / 2;
  const int* src = ei;
  const int* dst = ei + nE;

  char* w = (char*)d_ws;
  size_t off = 0;
  auto alloc = [&](size_t bytes) {
    void* p = (void*)(w + off);
    off = (off + bytes + 255) & ~(size_t)255;
    return p;
  };
  unsigned short* hraw = (unsigned short*)alloc((size_t)nN * HDIM * 2);
  unsigned short* hA = (unsigned short*)alloc((size_t)nN * HDIM * 2);
  unsigned short* hB = (unsigned short*)alloc((size_t)nN * HDIM * 2);
  float2* P = (float2*)alloc((size_t)nN * 8);
  float2* Q = (float2*)alloc((size_t)nN * 8);
  float* selfc = (float*)alloc((size_t)nN * 4);
  float* dinv = (float*)alloc((size_t)nN * 4);
  float* al = (float*)alloc((size_t)nN * 4);
  float* ar = (float*)alloc((size_t)nN * 4);
  int* indeg = (int*)alloc((size_t)nN * 4);
  int* rank = (int*)alloc((size_t)nE * 4);
  int* rowptr = (int*)alloc((size_t)(nN + 1) * 4);
  u64* csr_sd = (u64*)alloc((size_t)nE * 8);
  u64* esc = (u64*)alloc((size_t)nE * 8);
  int* bsum = (int*)alloc(1024);
  int* bpre = (int*)alloc(1024);

  const int nb_n = (nN + 255) / 256;
  const int nb_e = (nE + 255) / 256;
  const int nblk = (nN + 511) / 512;  // 98 <= 128
  const int nb4 = (nN + 3) / 4;

  // lin1 first (independent of graph), fused layer-0 scores
  k_lin1<<<(nN + 63) / 64, 256, 0, stream>>>(x, W1, b1, attl, attr, hraw, al, ar, nN);
  // CSR build (atomic-free scatter)
  k_init<<<nb_n, 256, 0, stream>>>(indeg, nN);
  k_hist<<<nb_e, 256, 0, stream>>>(dst, indeg, rank, nE);
  k_bsum<<<nblk, 256, 0, stream>>>(indeg, bsum, nN);
  k_bscan<<<1, 128, 0, stream>>>(bsum, bpre, rowptr, nblk, nN, nE);
  k_rowptr<<<nblk, 512, 0, stream>>>(indeg, bpre, al, ar, rowptr, dinv, P, Q, selfc, nN);
  k_scatter<<<nb_e, 256, 0, stream>>>(src, dst, rank, rowptr, csr_sd, nE);

  const unsigned short* hin = hraw;
  unsigned short* hout = hA;
  for (int l = 0; l < NLAYER; ++l) {
    k_coef<<<nb_e, 256, 0, stream>>>(csr_sd, P, Q, esc, nE);
    if (l < NLAYER - 1) {
      k_agg<true><<<nb4, 256, 0, stream>>>(hin, hraw, rowptr, esc, dinv, selfc,
                                           attl + (l + 1) * HDIM, attr + (l + 1) * HDIM,
                                           P, Q, hout, nN);
    } else {
      k_agg<false><<<nb4, 256, 0, stream>>>(hin, hraw, rowptr, esc, dinv, selfc,
                                            nullptr, nullptr, P, Q, hout, nN);
    }
    hin = hout;
    hout = (hout == hA) ? hB : hA;
  }
  k_out<<<nb_n, 256, 0, stream>>>(hin, W2, b2, out, nN);
}